// Round 2
// baseline (123.387 us; speedup 1.0000x reference)
//
#include <hip/hip_runtime.h>
#include <math.h>

// Sizes
#define B_SZ   16
#define CIN    384
#define NPIX   3136      // 56*56
#define OCH    1920      // N_GROUPS*D
#define P_TOT  848       // 16*49 + 16*4
#define P_PAD  896       // padded to multiple of 64

// ---------------------------------------------------------------------------
// Kernel 1: pool x (16,384,56,56) -> x_cat[k=384][p=896]
//   p in [0,784): B*49 + n   (7x7 agent pool, mean of 8x8)
//   p in [784,848): 784 + B*4 + m (2x2 cluster pool, mean of 28x28)
// ---------------------------------------------------------------------------
__global__ __launch_bounds__(256) void k_pool(const float* __restrict__ x,
                                              float* __restrict__ x_cat) {
    int blk = blockIdx.x;          // 16*384
    int Bi = blk / CIN;
    int ch = blk - Bi * CIN;
    __shared__ float ps[56][14];   // per-row sums of 4-col blocks
    __shared__ float s14[14][14];  // 4x4 block sums
    const float* xp = x + (size_t)(Bi * CIN + ch) * NPIX;
    int t = threadIdx.x;
    for (int p = t; p < 784; p += 256) {
        int row = p / 14, cb = p % 14;
        const float4 v = *reinterpret_cast<const float4*>(xp + row * 56 + cb * 4);
        ps[row][cb] = v.x + v.y + v.z + v.w;
    }
    __syncthreads();
    if (t < 196) {
        int ri = t / 14, cb = t % 14;
        s14[ri][cb] = ps[4*ri][cb] + ps[4*ri+1][cb] + ps[4*ri+2][cb] + ps[4*ri+3][cb];
    }
    __syncthreads();
    if (t < 49) {
        int i = t / 7, j = t % 7;
        float s = s14[2*i][2*j] + s14[2*i][2*j+1] + s14[2*i+1][2*j] + s14[2*i+1][2*j+1];
        x_cat[(size_t)ch * P_PAD + Bi * 49 + t] = s * (1.0f / 64.0f);
    } else if (t >= 64 && t < 68) {
        int m = t - 64;
        int mi = m / 2, mj = m % 2;
        float s = 0.f;
        for (int ri = 7*mi; ri < 7*mi + 7; ++ri)
            for (int cb = 7*mj; cb < 7*mj + 7; ++cb)
                s += s14[ri][cb];
        x_cat[(size_t)ch * P_PAD + 784 + Bi * 4 + m] = s * (1.0f / 784.0f);
    } else if (t >= 128 && t < 176 && Bi == 0) {
        // zero the pad columns once per channel row
        x_cat[(size_t)ch * P_PAD + 848 + (t - 128)] = 0.f;
    }
}

// ---------------------------------------------------------------------------
// Kernel 2: y_cat[1920][896] = proj_w[1920][384] @ x_cat[384][896] + proj_b
// classic fp32 tiled SGEMM, BM=BN=64, BK=16, 256 threads, 4x4 microtile
// ---------------------------------------------------------------------------
__global__ __launch_bounds__(256) void k_gemm1(const float* __restrict__ W,
                                               const float* __restrict__ bias,
                                               const float* __restrict__ x_cat,
                                               float* __restrict__ y_cat) {
    __shared__ float As[16][68];
    __shared__ float Bs[16][68];
    int n0 = blockIdx.x * 64, m0 = blockIdx.y * 64;
    int t = threadIdx.x;
    int tn = t & 15, tm = t >> 4;
    float acc[4][4] = {};
    for (int k0 = 0; k0 < 384; k0 += 16) {
        {
            int mm = t >> 2, kk4 = (t & 3) * 4;
            const float4 a = *reinterpret_cast<const float4*>(W + (size_t)(m0 + mm) * 384 + k0 + kk4);
            As[kk4][mm] = a.x; As[kk4+1][mm] = a.y; As[kk4+2][mm] = a.z; As[kk4+3][mm] = a.w;
        }
        {
            int kk = t >> 4, nn4 = (t & 15) * 4;
            const float4 b = *reinterpret_cast<const float4*>(x_cat + (size_t)(k0 + kk) * P_PAD + n0 + nn4);
            *reinterpret_cast<float4*>(&Bs[kk][nn4]) = b;
        }
        __syncthreads();
#pragma unroll
        for (int kk = 0; kk < 16; ++kk) {
            float4 a4 = *reinterpret_cast<const float4*>(&As[kk][tm * 4]);
            float4 b4 = *reinterpret_cast<const float4*>(&Bs[kk][tn * 4]);
            float av[4] = {a4.x, a4.y, a4.z, a4.w};
            float bv[4] = {b4.x, b4.y, b4.z, b4.w};
#pragma unroll
            for (int i = 0; i < 4; ++i)
#pragma unroll
                for (int j = 0; j < 4; ++j)
                    acc[i][j] += av[i] * bv[j];
        }
        __syncthreads();
    }
#pragma unroll
    for (int i = 0; i < 4; ++i) {
        float bb = bias[m0 + tm * 4 + i];
        float4 o;
        o.x = acc[i][0] + bb; o.y = acc[i][1] + bb;
        o.z = acc[i][2] + bb; o.w = acc[i][3] + bb;
        *reinterpret_cast<float4*>(y_cat + (size_t)(m0 + tm * 4 + i) * P_PAD + n0 + tn * 4) = o;
    }
}

// ---------------------------------------------------------------------------
// Kernel 3: per-(B,head) cluster attention -> osmall[16][384][49]
// 512 threads (phases need up to 392 concurrent work items)
// ---------------------------------------------------------------------------
__global__ __launch_bounds__(512) void k_attn(const float* __restrict__ y_cat,
                                              const float* __restrict__ alpha,
                                              const float* __restrict__ beta,
                                              float* __restrict__ osmall) {
    int bb = blockIdx.x;           // 128
    int Bi = bb >> 3, head = bb & 7;
    __shared__ float kL[2][48][49];
    __shared__ float vL[2][49][48];
    __shared__ float pL[48][49];
    __shared__ float kcL[2][4][48], vcL[2][4][48];
    __shared__ float e0[4][49], memb[4][49];
    __shared__ float rowmax0[4], esum0[4], msum[4];
    __shared__ float agg[8][48];
    __shared__ float anorm[8], pnorm[49];
    __shared__ float assignW[8][49];
    int t = threadIdx.x;
    size_t colbase = (size_t)Bi * 49;

    for (int idx = t; idx < 5 * 2352; idx += 512) {
        int g = idx / 2352, rem = idx % 2352;
        int cc = rem / 49, n = rem % 49;
        float v = y_cat[(size_t)(g * 384 + head * 48 + cc) * P_PAD + colbase + n];
        if (g == 0)      pL[cc][n] = v;
        else if (g == 1) kL[0][cc][n] = v;
        else if (g == 2) vL[0][n][cc] = v;
        else if (g == 3) kL[1][cc][n] = v;
        else             vL[1][n][cc] = v;
    }
    for (int idx = t; idx < 768; idx += 512) {
        int i = idx / 384, rem = idx % 384;
        int kv = rem / 192, rem2 = rem % 192;
        int m = rem2 / 48, cc = rem2 % 48;
        float v = y_cat[(size_t)((1 + 2*i + kv) * 384 + head * 48 + cc) * P_PAD + 784 + Bi * 4 + m];
        if (kv == 0) kcL[i][m][cc] = v; else vcL[i][m][cc] = v;
    }
    __syncthreads();

    const float scale = 0.14433756729740643f;  // 1/sqrt(48)
    if (t < 392) {
        int i = t / 196, r = t % 196;
        int m = r / 49, n = r % 49;
        float s = 0.f;
        for (int cc = 0; cc < 48; ++cc) s += kcL[i][m][cc] * kL[i][cc][n];
        s *= scale;
        if (i == 0) e0[m][n] = s; else memb[m][n] = s;
    }
    __syncthreads();
    if (t < 4) {
        float mx = -1e30f;
        for (int n = 0; n < 49; ++n) mx = fmaxf(mx, e0[t][n]);
        rowmax0[t] = mx;
    }
    __syncthreads();
    if (t < 196) { int m = t / 49, n = t % 49; e0[m][n] = expf(e0[m][n] - rowmax0[m]); }
    __syncthreads();
    if (t < 4) { float s = 0.f; for (int n = 0; n < 49; ++n) s += e0[t][n]; esum0[t] = s; }
    if (t >= 64 && t < 113) {       // module-1 softmax over m (per column n)
        int n = t - 64;
        float a0 = memb[0][n], a1 = memb[1][n], a2 = memb[2][n], a3 = memb[3][n];
        float mx = fmaxf(fmaxf(a0, a1), fmaxf(a2, a3));
        float x0 = expf(a0 - mx), x1 = expf(a1 - mx), x2 = expf(a2 - mx), x3 = expf(a3 - mx);
        float s = x0 + x1 + x2 + x3;
        memb[0][n] = x0 / s; memb[1][n] = x1 / s; memb[2][n] = x2 / s; memb[3][n] = x3 / s;
    }
    __syncthreads();
    if (t < 4) { float s = 0.f; for (int n = 0; n < 49; ++n) s += memb[t][n]; msum[t] = s; }
    __syncthreads();
    if (t < 384) {
        int row = t / 48, cc = t % 48;
        float acc = 0.f;
        if (row < 4) {
            for (int n = 0; n < 49; ++n) acc += e0[row][n] * vL[0][n][cc];
            agg[row][cc] = acc / esum0[row] + vcL[0][row][cc];
        } else {
            int m = row - 4;
            for (int n = 0; n < 49; ++n) acc += memb[m][n] * vL[1][n][cc];
            agg[row][cc] = acc / (msum[m] + 1e-6f) + vcL[1][m][cc];
        }
    }
    __syncthreads();
    if (t < 8) {
        float s = 0.f;
        for (int cc = 0; cc < 48; ++cc) { float a = agg[t][cc]; s += a * a; }
        anorm[t] = sqrtf(s) + 1e-6f;
    }
    if (t >= 64 && t < 113) {
        int n = t - 64; float s = 0.f;
        for (int cc = 0; cc < 48; ++cc) { float a = pL[cc][n]; s += a * a; }
        pnorm[n] = sqrtf(s) + 1e-6f;
    }
    __syncthreads();
    if (t < 49) {
        int n = t;
        float sims[8];
        float mx = -1e30f;
        for (int m = 0; m < 8; ++m) {
            float dot = 0.f;
            for (int cc = 0; cc < 48; ++cc) dot += agg[m][cc] * pL[cc][n];
            float sv = alpha[m] * (dot / (anorm[m] * pnorm[n])) + beta[m];
            sims[m] = sv; mx = fmaxf(mx, sv);
        }
        float ssum = 0.f;
        for (int m = 0; m < 8; ++m) { float e = expf(sims[m] - mx); sims[m] = e; ssum += e; }
        for (int m = 0; m < 8; ++m) assignW[m][n] = sims[m] / ssum;
    }
    __syncthreads();
    for (int idx = t; idx < 2352; idx += 512) {
        int cc = idx / 49, n = idx % 49;
        float s = 0.f;
        for (int m = 0; m < 8; ++m) s += agg[m][cc] * assignW[m][n];
        osmall[((size_t)Bi * 384 + head * 48 + cc) * 49 + n] = s;
    }
}

// ---------------------------------------------------------------------------
// Kernel 4: z = proj2 @ osmall (+bias) at 7x7, then bilinear 7x7 -> 56x56
// one block per (B, 16-row o-tile): 16*24 = 384 blocks
// ---------------------------------------------------------------------------
__global__ __launch_bounds__(256) void k_out(const float* __restrict__ osmall,
                                             const float* __restrict__ W2,
                                             const float* __restrict__ b2,
                                             float* __restrict__ out) {
    int blk = blockIdx.x;
    int Bi = blk / 24, ot = blk % 24;
    __shared__ float Wt[16][384];
    __shared__ float Os[128][49];
    __shared__ float zL[16][49];
    int t = threadIdx.x;
    for (int idx = t; idx < 16 * 384; idx += 256) {
        int r = idx / 384, k = idx % 384;
        Wt[r][k] = W2[(size_t)(ot * 16 + r) * 384 + k];
    }
    float acc[4] = {0.f, 0.f, 0.f, 0.f};
    int n = t % 49, rq = t / 49;   // valid when t<196
    for (int c = 0; c < 3; ++c) {
        __syncthreads();
        for (int idx = t; idx < 128 * 49; idx += 256) {
            int kk = idx / 49, nn = idx % 49;
            Os[kk][nn] = osmall[((size_t)Bi * 384 + c * 128 + kk) * 49 + nn];
        }
        __syncthreads();
        if (t < 196) {
            for (int kk = 0; kk < 128; ++kk) {
                float o = Os[kk][n];
#pragma unroll
                for (int j = 0; j < 4; ++j)
                    acc[j] += Wt[rq * 4 + j][c * 128 + kk] * o;
            }
        }
    }
    __syncthreads();
    if (t < 196) {
#pragma unroll
        for (int j = 0; j < 4; ++j)
            zL[rq * 4 + j][n] = acc[j] + b2[ot * 16 + rq * 4 + j];
    }
    __syncthreads();
    size_t obase = ((size_t)Bi * 384 + ot * 16) * (size_t)NPIX;
    for (int it = 0; it < 196; ++it) {
        int pidx = it * 256 + t;
        int ol = pidx / NPIX, hw = pidx % NPIX;
        int h = hw / 56, w = hw % 56;
        float sh = (h - 3.5f) * 0.125f;
        float sw = (w - 3.5f) * 0.125f;
        int ih0, iw0; float fh, fw;
        if (sh <= 0.f)      { ih0 = 0; fh = 0.f; }
        else if (sh >= 6.f) { ih0 = 6; fh = 0.f; }
        else                { ih0 = (int)sh; fh = sh - (float)ih0; }
        if (sw <= 0.f)      { iw0 = 0; fw = 0.f; }
        else if (sw >= 6.f) { iw0 = 6; fw = 0.f; }
        else                { iw0 = (int)sw; fw = sw - (float)iw0; }
        int ih1 = min(ih0 + 1, 6), iw1 = min(iw0 + 1, 6);
        float z00 = zL[ol][ih0 * 7 + iw0], z01 = zL[ol][ih0 * 7 + iw1];
        float z10 = zL[ol][ih1 * 7 + iw0], z11 = zL[ol][ih1 * 7 + iw1];
        float v0 = z00 + fw * (z01 - z00);
        float v1 = z10 + fw * (z11 - z10);
        out[obase + (size_t)pidx] = v0 + fh * (v1 - v0);
    }
}

// ---------------------------------------------------------------------------
extern "C" void kernel_launch(void* const* d_in, const int* in_sizes, int n_in,
                              void* d_out, int out_size, void* d_ws, size_t ws_size,
                              hipStream_t stream) {
    const float* x      = (const float*)d_in[0];
    const float* proj_w = (const float*)d_in[1];
    const float* proj_b = (const float*)d_in[2];
    const float* alpha  = (const float*)d_in[3];
    const float* beta   = (const float*)d_in[4];
    const float* w2     = (const float*)d_in[5];
    const float* b2     = (const float*)d_in[6];
    float* out = (float*)d_out;
    float* ws  = (float*)d_ws;

    float* x_cat  = ws;                          // 384*896   = 344064 floats
    float* y_cat  = ws + (size_t)384 * P_PAD;    // 1920*896  = 1720320 floats
    float* osmall = y_cat + (size_t)OCH * P_PAD; // 16*384*49 = 301056 floats
    // total ws usage: ~9.5 MB

    k_pool <<<dim3(6144),   256, 0, stream>>>(x, x_cat);
    k_gemm1<<<dim3(14, 30), 256, 0, stream>>>(proj_w, proj_b, x_cat, y_cat);
    k_attn <<<dim3(128),    512, 0, stream>>>(y_cat, alpha, beta, osmall);
    k_out  <<<dim3(384),    256, 0, stream>>>(osmall, w2, b2, out);
}

// Round 3
// 101.444 us; speedup vs baseline: 1.2163x; 1.2163x over previous
//
#include <hip/hip_runtime.h>
#include <math.h>

// Sizes
#define B_SZ   16
#define CIN    384
#define NPIX   3136      // 56*56
#define OCH    1920      // N_GROUPS*D
#define P_TOT  848       // 16*49 + 16*4
#define P_PAD  896       // padded to multiple of 64

// ---------------------------------------------------------------------------
// Kernel 1: pool x (16,384,56,56) -> x_cat[k=384][p=896]
//   p in [0,784): B*49 + n   (7x7 agent pool, mean of 8x8)
//   p in [784,848): 784 + B*4 + m (2x2 cluster pool, mean of 28x28)
// ---------------------------------------------------------------------------
__global__ __launch_bounds__(256) void k_pool(const float* __restrict__ x,
                                              float* __restrict__ x_cat) {
    int blk = blockIdx.x;          // 16*384
    int Bi = blk / CIN;
    int ch = blk - Bi * CIN;
    __shared__ float ps[56][14];   // per-row sums of 4-col blocks
    __shared__ float s14[14][14];  // 4x4 block sums
    const float* xp = x + (size_t)(Bi * CIN + ch) * NPIX;
    int t = threadIdx.x;
    for (int p = t; p < 784; p += 256) {
        int row = p / 14, cb = p % 14;
        const float4 v = *reinterpret_cast<const float4*>(xp + row * 56 + cb * 4);
        ps[row][cb] = v.x + v.y + v.z + v.w;
    }
    __syncthreads();
    if (t < 196) {
        int ri = t / 14, cb = t % 14;
        s14[ri][cb] = ps[4*ri][cb] + ps[4*ri+1][cb] + ps[4*ri+2][cb] + ps[4*ri+3][cb];
    }
    __syncthreads();
    if (t < 49) {
        int i = t / 7, j = t % 7;
        float s = s14[2*i][2*j] + s14[2*i][2*j+1] + s14[2*i+1][2*j] + s14[2*i+1][2*j+1];
        x_cat[(size_t)ch * P_PAD + Bi * 49 + t] = s * (1.0f / 64.0f);
    } else if (t >= 64 && t < 68) {
        int m = t - 64;
        int mi = m / 2, mj = m % 2;
        float s = 0.f;
        for (int ri = 7*mi; ri < 7*mi + 7; ++ri)
            for (int cb = 7*mj; cb < 7*mj + 7; ++cb)
                s += s14[ri][cb];
        x_cat[(size_t)ch * P_PAD + 784 + Bi * 4 + m] = s * (1.0f / 784.0f);
    } else if (t >= 128 && t < 176 && Bi == 0) {
        x_cat[(size_t)ch * P_PAD + 848 + (t - 128)] = 0.f;
    }
}

// ---------------------------------------------------------------------------
// Kernel 2: y_cat[1920][896] = proj_w[1920][384] @ x_cat[384][896] + proj_b
// ---------------------------------------------------------------------------
__global__ __launch_bounds__(256) void k_gemm1(const float* __restrict__ W,
                                               const float* __restrict__ bias,
                                               const float* __restrict__ x_cat,
                                               float* __restrict__ y_cat) {
    __shared__ float As[16][68];
    __shared__ float Bs[16][68];
    int n0 = blockIdx.x * 64, m0 = blockIdx.y * 64;
    int t = threadIdx.x;
    int tn = t & 15, tm = t >> 4;
    float acc[4][4] = {};
    for (int k0 = 0; k0 < 384; k0 += 16) {
        {
            int mm = t >> 2, kk4 = (t & 3) * 4;
            const float4 a = *reinterpret_cast<const float4*>(W + (size_t)(m0 + mm) * 384 + k0 + kk4);
            As[kk4][mm] = a.x; As[kk4+1][mm] = a.y; As[kk4+2][mm] = a.z; As[kk4+3][mm] = a.w;
        }
        {
            int kk = t >> 4, nn4 = (t & 15) * 4;
            const float4 b = *reinterpret_cast<const float4*>(x_cat + (size_t)(k0 + kk) * P_PAD + n0 + nn4);
            *reinterpret_cast<float4*>(&Bs[kk][nn4]) = b;
        }
        __syncthreads();
#pragma unroll
        for (int kk = 0; kk < 16; ++kk) {
            float4 a4 = *reinterpret_cast<const float4*>(&As[kk][tm * 4]);
            float4 b4 = *reinterpret_cast<const float4*>(&Bs[kk][tn * 4]);
            float av[4] = {a4.x, a4.y, a4.z, a4.w};
            float bv[4] = {b4.x, b4.y, b4.z, b4.w};
#pragma unroll
            for (int i = 0; i < 4; ++i)
#pragma unroll
                for (int j = 0; j < 4; ++j)
                    acc[i][j] += av[i] * bv[j];
        }
        __syncthreads();
    }
#pragma unroll
    for (int i = 0; i < 4; ++i) {
        float bb = bias[m0 + tm * 4 + i];
        float4 o;
        o.x = acc[i][0] + bb; o.y = acc[i][1] + bb;
        o.z = acc[i][2] + bb; o.w = acc[i][3] + bb;
        *reinterpret_cast<float4*>(y_cat + (size_t)(m0 + tm * 4 + i) * P_PAD + n0 + tn * 4) = o;
    }
}

// ---------------------------------------------------------------------------
// Kernel 3: per-(B,head) cluster attention -> osmall[16][384][49]
// ---------------------------------------------------------------------------
__global__ __launch_bounds__(512) void k_attn(const float* __restrict__ y_cat,
                                              const float* __restrict__ alpha,
                                              const float* __restrict__ beta,
                                              float* __restrict__ osmall) {
    int bb = blockIdx.x;           // 128
    int Bi = bb >> 3, head = bb & 7;
    __shared__ float kL[2][48][49];
    __shared__ float vL[2][49][48];
    __shared__ float pL[48][49];
    __shared__ float kcL[2][4][48], vcL[2][4][48];
    __shared__ float e0[4][49], memb[4][49];
    __shared__ float rowmax0[4], esum0[4], msum[4];
    __shared__ float agg[8][48];
    __shared__ float anorm[8], pnorm[49];
    __shared__ float assignW[8][49];
    int t = threadIdx.x;
    size_t colbase = (size_t)Bi * 49;

    for (int idx = t; idx < 5 * 2352; idx += 512) {
        int g = idx / 2352, rem = idx % 2352;
        int cc = rem / 49, n = rem % 49;
        float v = y_cat[(size_t)(g * 384 + head * 48 + cc) * P_PAD + colbase + n];
        if (g == 0)      pL[cc][n] = v;
        else if (g == 1) kL[0][cc][n] = v;
        else if (g == 2) vL[0][n][cc] = v;
        else if (g == 3) kL[1][cc][n] = v;
        else             vL[1][n][cc] = v;
    }
    for (int idx = t; idx < 768; idx += 512) {
        int i = idx / 384, rem = idx % 384;
        int kv = rem / 192, rem2 = rem % 192;
        int m = rem2 / 48, cc = rem2 % 48;
        float v = y_cat[(size_t)((1 + 2*i + kv) * 384 + head * 48 + cc) * P_PAD + 784 + Bi * 4 + m];
        if (kv == 0) kcL[i][m][cc] = v; else vcL[i][m][cc] = v;
    }
    __syncthreads();

    const float scale = 0.14433756729740643f;  // 1/sqrt(48)
    if (t < 392) {
        int i = t / 196, r = t % 196;
        int m = r / 49, n = r % 49;
        float s = 0.f;
        for (int cc = 0; cc < 48; ++cc) s += kcL[i][m][cc] * kL[i][cc][n];
        s *= scale;
        if (i == 0) e0[m][n] = s; else memb[m][n] = s;
    }
    __syncthreads();
    if (t < 4) {
        float mx = -1e30f;
        for (int n = 0; n < 49; ++n) mx = fmaxf(mx, e0[t][n]);
        rowmax0[t] = mx;
    }
    __syncthreads();
    if (t < 196) { int m = t / 49, n = t % 49; e0[m][n] = expf(e0[m][n] - rowmax0[m]); }
    __syncthreads();
    if (t < 4) { float s = 0.f; for (int n = 0; n < 49; ++n) s += e0[t][n]; esum0[t] = s; }
    if (t >= 64 && t < 113) {       // module-1 softmax over m (per column n)
        int n = t - 64;
        float a0 = memb[0][n], a1 = memb[1][n], a2 = memb[2][n], a3 = memb[3][n];
        float mx = fmaxf(fmaxf(a0, a1), fmaxf(a2, a3));
        float x0 = expf(a0 - mx), x1 = expf(a1 - mx), x2 = expf(a2 - mx), x3 = expf(a3 - mx);
        float s = x0 + x1 + x2 + x3;
        memb[0][n] = x0 / s; memb[1][n] = x1 / s; memb[2][n] = x2 / s; memb[3][n] = x3 / s;
    }
    __syncthreads();
    if (t < 4) { float s = 0.f; for (int n = 0; n < 49; ++n) s += memb[t][n]; msum[t] = s; }
    __syncthreads();
    if (t < 384) {
        int row = t / 48, cc = t % 48;
        float acc = 0.f;
        if (row < 4) {
            for (int n = 0; n < 49; ++n) acc += e0[row][n] * vL[0][n][cc];
            agg[row][cc] = acc / esum0[row] + vcL[0][row][cc];
        } else {
            int m = row - 4;
            for (int n = 0; n < 49; ++n) acc += memb[m][n] * vL[1][n][cc];
            agg[row][cc] = acc / (msum[m] + 1e-6f) + vcL[1][m][cc];
        }
    }
    __syncthreads();
    if (t < 8) {
        float s = 0.f;
        for (int cc = 0; cc < 48; ++cc) { float a = agg[t][cc]; s += a * a; }
        anorm[t] = sqrtf(s) + 1e-6f;
    }
    if (t >= 64 && t < 113) {
        int n = t - 64; float s = 0.f;
        for (int cc = 0; cc < 48; ++cc) { float a = pL[cc][n]; s += a * a; }
        pnorm[n] = sqrtf(s) + 1e-6f;
    }
    __syncthreads();
    if (t < 49) {
        int n = t;
        float sims[8];
        float mx = -1e30f;
        for (int m = 0; m < 8; ++m) {
            float dot = 0.f;
            for (int cc = 0; cc < 48; ++cc) dot += agg[m][cc] * pL[cc][n];
            float sv = alpha[m] * (dot / (anorm[m] * pnorm[n])) + beta[m];
            sims[m] = sv; mx = fmaxf(mx, sv);
        }
        float ssum = 0.f;
        for (int m = 0; m < 8; ++m) { float e = expf(sims[m] - mx); sims[m] = e; ssum += e; }
        for (int m = 0; m < 8; ++m) assignW[m][n] = sims[m] / ssum;
    }
    __syncthreads();
    for (int idx = t; idx < 2352; idx += 512) {
        int cc = idx / 49, n = idx % 49;
        float s = 0.f;
        for (int m = 0; m < 8; ++m) s += agg[m][cc] * assignW[m][n];
        osmall[((size_t)Bi * 384 + head * 48 + cc) * 49 + n] = s;
    }
}

// ---------------------------------------------------------------------------
// Kernel 4: z[16][384][49] = proj2 @ osmall + bias (at 7x7 only)
// one block per (B, 16-row o-tile): 384 blocks
// ---------------------------------------------------------------------------
__global__ __launch_bounds__(256) void k_gemm2(const float* __restrict__ osmall,
                                               const float* __restrict__ W2,
                                               const float* __restrict__ b2,
                                               float* __restrict__ z) {
    int blk = blockIdx.x;
    int Bi = blk / 24, ot = blk % 24;
    __shared__ float Wt[16][384];
    __shared__ float Os[128][49];
    int t = threadIdx.x;
    for (int idx = t; idx < 16 * 384; idx += 256) {
        int r = idx / 384, k = idx % 384;
        Wt[r][k] = W2[(size_t)(ot * 16 + r) * 384 + k];
    }
    float acc[4] = {0.f, 0.f, 0.f, 0.f};
    int n = t % 49, rq = t / 49;   // valid when t<196
    for (int c = 0; c < 3; ++c) {
        __syncthreads();
        for (int idx = t; idx < 128 * 49; idx += 256) {
            int kk = idx / 49, nn = idx % 49;
            Os[kk][nn] = osmall[((size_t)Bi * 384 + c * 128 + kk) * 49 + nn];
        }
        __syncthreads();
        if (t < 196) {
            for (int kk = 0; kk < 128; ++kk) {
                float o = Os[kk][n];
#pragma unroll
                for (int j = 0; j < 4; ++j)
                    acc[j] += Wt[rq * 4 + j][c * 128 + kk] * o;
            }
        }
    }
    if (t < 196) {
#pragma unroll
        for (int j = 0; j < 4; ++j)
            z[((size_t)Bi * 384 + ot * 16 + rq * 4 + j) * 49 + n] =
                acc[j] + b2[ot * 16 + rq * 4 + j];
    }
}

// ---------------------------------------------------------------------------
// Kernel 5: bilinear 7x7 -> 56x56, one block per (B, ch) plane: 6144 blocks
// separable: lerp along h into tmp[56][7], then lerp along w, float4 stores
// ---------------------------------------------------------------------------
__global__ __launch_bounds__(256) void k_up(const float* __restrict__ z,
                                            float* __restrict__ out) {
    int blk = blockIdx.x;          // 16*384
    int Bi = blk / 384, ch = blk % 384;
    __shared__ float zL[49];
    __shared__ float tmp[56][8];   // +1 pad col
    int t = threadIdx.x;
    if (t < 49) zL[t] = z[((size_t)Bi * 384 + ch) * 49 + t];
    __syncthreads();
    for (int idx = t; idx < 392; idx += 256) {
        int h = idx / 7, iw = idx % 7;
        float sh = (h - 3.5f) * 0.125f;
        int ih0; float fh;
        if (sh <= 0.f)      { ih0 = 0; fh = 0.f; }
        else if (sh >= 6.f) { ih0 = 6; fh = 0.f; }
        else                { ih0 = (int)sh; fh = sh - (float)ih0; }
        int ih1 = min(ih0 + 1, 6);
        float z0 = zL[ih0 * 7 + iw];
        tmp[h][iw] = z0 + fh * (zL[ih1 * 7 + iw] - z0);
    }
    __syncthreads();
    size_t obase = ((size_t)Bi * 384 + ch) * (size_t)NPIX;
    for (int q = t; q < 784; q += 256) {          // 784 float4 quads
        int h = q / 14, qw = q % 14;
        float o[4];
#pragma unroll
        for (int j = 0; j < 4; ++j) {
            int w = qw * 4 + j;
            float sw = (w - 3.5f) * 0.125f;
            int iw0; float fw;
            if (sw <= 0.f)      { iw0 = 0; fw = 0.f; }
            else if (sw >= 6.f) { iw0 = 6; fw = 0.f; }
            else                { iw0 = (int)sw; fw = sw - (float)iw0; }
            int iw1 = min(iw0 + 1, 6);
            float t0 = tmp[h][iw0];
            o[j] = t0 + fw * (tmp[h][iw1] - t0);
        }
        float4 v; v.x = o[0]; v.y = o[1]; v.z = o[2]; v.w = o[3];
        *reinterpret_cast<float4*>(out + obase + (size_t)q * 4) = v;
    }
}

// ---------------------------------------------------------------------------
extern "C" void kernel_launch(void* const* d_in, const int* in_sizes, int n_in,
                              void* d_out, int out_size, void* d_ws, size_t ws_size,
                              hipStream_t stream) {
    const float* x      = (const float*)d_in[0];
    const float* proj_w = (const float*)d_in[1];
    const float* proj_b = (const float*)d_in[2];
    const float* alpha  = (const float*)d_in[3];
    const float* beta   = (const float*)d_in[4];
    const float* w2     = (const float*)d_in[5];
    const float* b2     = (const float*)d_in[6];
    float* out = (float*)d_out;
    float* ws  = (float*)d_ws;

    float* x_cat  = ws;                          // 384*896   = 344064 floats
    float* y_cat  = ws + (size_t)384 * P_PAD;    // 1920*896  = 1720320 floats
    float* osmall = y_cat + (size_t)OCH * P_PAD; // 16*384*49 = 301056 floats
    float* z      = x_cat;                       // reuse (dead after k_gemm1): 301056 <= 344064
    // total ws usage: ~9.5 MB

    k_pool <<<dim3(6144),   256, 0, stream>>>(x, x_cat);
    k_gemm1<<<dim3(14, 30), 256, 0, stream>>>(proj_w, proj_b, x_cat, y_cat);
    k_attn <<<dim3(128),    512, 0, stream>>>(y_cat, alpha, beta, osmall);
    k_gemm2<<<dim3(384),    256, 0, stream>>>(osmall, w2, b2, z);
    k_up   <<<dim3(6144),   256, 0, stream>>>(z, out);
}

// Round 4
// 90.274 us; speedup vs baseline: 1.3668x; 1.1237x over previous
//
#include <hip/hip_runtime.h>
#include <math.h>

// Sizes
#define B_SZ   16
#define CIN    384
#define NPIX   3136      // 56*56
#define OCH    1920      // N_GROUPS*D
#define P_PAD  896       // padded columns of x_cat/y_cat
#define ZPSTR  319488    // 16*384*52, one split-K partial plane (floats)

typedef float vf4 __attribute__((ext_vector_type(4)));

// ---------------------------------------------------------------------------
// Kernel 1: pool x (16,384,56,56) -> x_cat[k=384][p=896]
// ---------------------------------------------------------------------------
__global__ __launch_bounds__(256) void k_pool(const float* __restrict__ x,
                                              float* __restrict__ x_cat) {
    int blk = blockIdx.x;          // 16*384
    int Bi = blk / CIN;
    int ch = blk - Bi * CIN;
    __shared__ float ps[56][14];   // per-row sums of 4-col blocks
    __shared__ float s14[14][14];  // 4x4 block sums
    const float* xp = x + (size_t)(Bi * CIN + ch) * NPIX;
    int t = threadIdx.x;
    for (int p = t; p < 784; p += 256) {
        int row = p / 14, cb = p % 14;
        const vf4 v = __builtin_nontemporal_load(
            reinterpret_cast<const vf4*>(xp + row * 56 + cb * 4));
        ps[row][cb] = v.x + v.y + v.z + v.w;
    }
    __syncthreads();
    if (t < 196) {
        int ri = t / 14, cb = t % 14;
        s14[ri][cb] = ps[4*ri][cb] + ps[4*ri+1][cb] + ps[4*ri+2][cb] + ps[4*ri+3][cb];
    }
    __syncthreads();
    if (t < 49) {
        int i = t / 7, j = t % 7;
        float s = s14[2*i][2*j] + s14[2*i][2*j+1] + s14[2*i+1][2*j] + s14[2*i+1][2*j+1];
        x_cat[(size_t)ch * P_PAD + Bi * 49 + t] = s * (1.0f / 64.0f);
    } else if (t >= 64 && t < 68) {
        int m = t - 64;
        int mi = m / 2, mj = m % 2;
        float s = 0.f;
        for (int ri = 7*mi; ri < 7*mi + 7; ++ri)
            for (int cb = 7*mj; cb < 7*mj + 7; ++cb)
                s += s14[ri][cb];
        x_cat[(size_t)ch * P_PAD + 784 + Bi * 4 + m] = s * (1.0f / 784.0f);
    } else if (t >= 128 && t < 176 && Bi == 0) {
        x_cat[(size_t)ch * P_PAD + 848 + (t - 128)] = 0.f;
    }
}

// ---------------------------------------------------------------------------
// Kernel 2: y_cat[1920][896] = proj_w[1920][384] @ x_cat[384][896] + proj_b
// ---------------------------------------------------------------------------
__global__ __launch_bounds__(256) void k_gemm1(const float* __restrict__ W,
                                               const float* __restrict__ bias,
                                               const float* __restrict__ x_cat,
                                               float* __restrict__ y_cat) {
    __shared__ float As[16][68];
    __shared__ float Bs[16][68];
    int n0 = blockIdx.x * 64, m0 = blockIdx.y * 64;
    int t = threadIdx.x;
    int tn = t & 15, tm = t >> 4;
    float acc[4][4] = {};
    for (int k0 = 0; k0 < 384; k0 += 16) {
        {
            int mm = t >> 2, kk4 = (t & 3) * 4;
            const float4 a = *reinterpret_cast<const float4*>(W + (size_t)(m0 + mm) * 384 + k0 + kk4);
            As[kk4][mm] = a.x; As[kk4+1][mm] = a.y; As[kk4+2][mm] = a.z; As[kk4+3][mm] = a.w;
        }
        {
            int kk = t >> 4, nn4 = (t & 15) * 4;
            const float4 b = *reinterpret_cast<const float4*>(x_cat + (size_t)(k0 + kk) * P_PAD + n0 + nn4);
            *reinterpret_cast<float4*>(&Bs[kk][nn4]) = b;
        }
        __syncthreads();
#pragma unroll
        for (int kk = 0; kk < 16; ++kk) {
            float4 a4 = *reinterpret_cast<const float4*>(&As[kk][tm * 4]);
            float4 b4 = *reinterpret_cast<const float4*>(&Bs[kk][tn * 4]);
            float av[4] = {a4.x, a4.y, a4.z, a4.w};
            float bv[4] = {b4.x, b4.y, b4.z, b4.w};
#pragma unroll
            for (int i = 0; i < 4; ++i)
#pragma unroll
                for (int j = 0; j < 4; ++j)
                    acc[i][j] += av[i] * bv[j];
        }
        __syncthreads();
    }
#pragma unroll
    for (int i = 0; i < 4; ++i) {
        float bb = bias[m0 + tm * 4 + i];
        float4 o;
        o.x = acc[i][0] + bb; o.y = acc[i][1] + bb;
        o.z = acc[i][2] + bb; o.w = acc[i][3] + bb;
        *reinterpret_cast<float4*>(y_cat + (size_t)(m0 + tm * 4 + i) * P_PAD + n0 + tn * 4) = o;
    }
}

// ---------------------------------------------------------------------------
// Kernel 3: per-(B,head) cluster attention -> osmall[16][384][49]
// ---------------------------------------------------------------------------
__global__ __launch_bounds__(512) void k_attn(const float* __restrict__ y_cat,
                                              const float* __restrict__ alpha,
                                              const float* __restrict__ beta,
                                              float* __restrict__ osmall) {
    int bb = blockIdx.x;           // 128
    int Bi = bb >> 3, head = bb & 7;
    __shared__ float kL[2][48][49];
    __shared__ float vL[2][49][48];
    __shared__ float pL[48][49];
    __shared__ float kcL[2][4][48], vcL[2][4][48];
    __shared__ float e0[4][49], memb[4][49];
    __shared__ float rowmax0[4], esum0[4], msum[4];
    __shared__ float agg[8][48];
    __shared__ float anorm[8], pnorm[49];
    __shared__ float assignW[8][49];
    int t = threadIdx.x;
    size_t colbase = (size_t)Bi * 49;

    for (int idx = t; idx < 5 * 2352; idx += 512) {
        int g = idx / 2352, rem = idx % 2352;
        int cc = rem / 49, n = rem % 49;
        float v = y_cat[(size_t)(g * 384 + head * 48 + cc) * P_PAD + colbase + n];
        if (g == 0)      pL[cc][n] = v;
        else if (g == 1) kL[0][cc][n] = v;
        else if (g == 2) vL[0][n][cc] = v;
        else if (g == 3) kL[1][cc][n] = v;
        else             vL[1][n][cc] = v;
    }
    for (int idx = t; idx < 768; idx += 512) {
        int i = idx / 384, rem = idx % 384;
        int kv = rem / 192, rem2 = rem % 192;
        int m = rem2 / 48, cc = rem2 % 48;
        float v = y_cat[(size_t)((1 + 2*i + kv) * 384 + head * 48 + cc) * P_PAD + 784 + Bi * 4 + m];
        if (kv == 0) kcL[i][m][cc] = v; else vcL[i][m][cc] = v;
    }
    __syncthreads();

    const float scale = 0.14433756729740643f;  // 1/sqrt(48)
    if (t < 392) {
        int i = t / 196, r = t % 196;
        int m = r / 49, n = r % 49;
        float s = 0.f;
        for (int cc = 0; cc < 48; ++cc) s += kcL[i][m][cc] * kL[i][cc][n];
        s *= scale;
        if (i == 0) e0[m][n] = s; else memb[m][n] = s;
    }
    __syncthreads();
    if (t < 4) {
        float mx = -1e30f;
        for (int n = 0; n < 49; ++n) mx = fmaxf(mx, e0[t][n]);
        rowmax0[t] = mx;
    }
    __syncthreads();
    if (t < 196) { int m = t / 49, n = t % 49; e0[m][n] = expf(e0[m][n] - rowmax0[m]); }
    __syncthreads();
    if (t < 4) { float s = 0.f; for (int n = 0; n < 49; ++n) s += e0[t][n]; esum0[t] = s; }
    if (t >= 64 && t < 113) {       // module-1 softmax over m (per column n)
        int n = t - 64;
        float a0 = memb[0][n], a1 = memb[1][n], a2 = memb[2][n], a3 = memb[3][n];
        float mx = fmaxf(fmaxf(a0, a1), fmaxf(a2, a3));
        float x0 = expf(a0 - mx), x1 = expf(a1 - mx), x2 = expf(a2 - mx), x3 = expf(a3 - mx);
        float s = x0 + x1 + x2 + x3;
        memb[0][n] = x0 / s; memb[1][n] = x1 / s; memb[2][n] = x2 / s; memb[3][n] = x3 / s;
    }
    __syncthreads();
    if (t < 4) { float s = 0.f; for (int n = 0; n < 49; ++n) s += memb[t][n]; msum[t] = s; }
    __syncthreads();
    if (t < 384) {
        int row = t / 48, cc = t % 48;
        float acc = 0.f;
        if (row < 4) {
            for (int n = 0; n < 49; ++n) acc += e0[row][n] * vL[0][n][cc];
            agg[row][cc] = acc / esum0[row] + vcL[0][row][cc];
        } else {
            int m = row - 4;
            for (int n = 0; n < 49; ++n) acc += memb[m][n] * vL[1][n][cc];
            agg[row][cc] = acc / (msum[m] + 1e-6f) + vcL[1][m][cc];
        }
    }
    __syncthreads();
    if (t < 8) {
        float s = 0.f;
        for (int cc = 0; cc < 48; ++cc) { float a = agg[t][cc]; s += a * a; }
        anorm[t] = sqrtf(s) + 1e-6f;
    }
    if (t >= 64 && t < 113) {
        int n = t - 64; float s = 0.f;
        for (int cc = 0; cc < 48; ++cc) { float a = pL[cc][n]; s += a * a; }
        pnorm[n] = sqrtf(s) + 1e-6f;
    }
    __syncthreads();
    if (t < 49) {
        int n = t;
        float sims[8];
        float mx = -1e30f;
        for (int m = 0; m < 8; ++m) {
            float dot = 0.f;
            for (int cc = 0; cc < 48; ++cc) dot += agg[m][cc] * pL[cc][n];
            float sv = alpha[m] * (dot / (anorm[m] * pnorm[n])) + beta[m];
            sims[m] = sv; mx = fmaxf(mx, sv);
        }
        float ssum = 0.f;
        for (int m = 0; m < 8; ++m) { float e = expf(sims[m] - mx); sims[m] = e; ssum += e; }
        for (int m = 0; m < 8; ++m) assignW[m][n] = sims[m] / ssum;
    }
    __syncthreads();
    for (int idx = t; idx < 2352; idx += 512) {
        int cc = idx / 49, n = idx % 49;
        float s = 0.f;
        for (int m = 0; m < 8; ++m) s += agg[m][cc] * assignW[m][n];
        osmall[((size_t)Bi * 384 + head * 48 + cc) * 49 + n] = s;
    }
}

// ---------------------------------------------------------------------------
// Kernel 4: split-K proj2 GEMM.
// grid 1536 = (Bi 16) x (ot 24: 16-row tiles) x (kc 4: K=96 chunks)
// zp[kc][Bi*384+o][52] partial = W2[o][kc*96..+96] @ osmall[Bi][kc*96..+96][49]
// 4x4 microtile, in-block 4-way ks split, LDS: Wt[16][97] + Os[96][52]
// ---------------------------------------------------------------------------
__global__ __launch_bounds__(256) void k_gemm2s(const float* __restrict__ osmall,
                                                const float* __restrict__ W2,
                                                float* __restrict__ zp) {
    int b = blockIdx.x;
    int kc = b & 3, ot = (b >> 2) % 24, Bi = b / 96;
    __shared__ float smem[1552 + 4992];   // Wt 16x97 | Os 96x52 (reused as zbuf)
    int t = threadIdx.x;
    // Wt[r0][c] = W2[ot*16+r0][kc*96+c]
    for (int idx = t; idx < 1536; idx += 256) {
        int r0 = idx / 96, c = idx - r0 * 96;
        smem[r0 * 97 + c] = W2[(size_t)(ot * 16 + r0) * 384 + kc * 96 + c];
    }
    // Os[kk][n] = osmall[Bi][kc*96+kk][n]; slab is contiguous & 16B aligned
    const float4* src4 = reinterpret_cast<const float4*>(
        osmall + (size_t)(Bi * 384 + kc * 96) * 49);
    for (int idx = t; idx < 1176; idx += 256) {
        float4 f = src4[idx];
        int e = idx * 4;
        float vv[4] = {f.x, f.y, f.z, f.w};
#pragma unroll
        for (int j = 0; j < 4; ++j) {
            int ee = e + j;
            int kk2 = ee / 49, n2 = ee - kk2 * 49;
            smem[1552 + kk2 * 52 + n2] = vv[j];
        }
    }
    if (t < 96) {  // zero pad cols
        int o = 1552 + t * 52;
        smem[o + 49] = 0.f; smem[o + 50] = 0.f; smem[o + 51] = 0.f;
    }
    __syncthreads();

    float4 acc0 = {0,0,0,0}, acc1 = {0,0,0,0}, acc2 = {0,0,0,0}, acc3 = {0,0,0,0};
    int ks = 0, rgq = 0, nq = 0;
    if (t < 208) {
        ks = t / 52; int rem = t - ks * 52; rgq = rem / 13; nq = rem - rgq * 13;
        const float* WtB = smem + rgq * 4 * 97 + ks;          // kk = ks + 4i
        const float* OsB = smem + 1552 + nq * 4 + ks * 52;
#pragma unroll
        for (int i = 0; i < 24; ++i) {
            float4 bb = *reinterpret_cast<const float4*>(OsB + i * 208);  // (ks+4i)*52
            float a0 = WtB[i * 4];
            float a1 = WtB[97  + i * 4];
            float a2 = WtB[194 + i * 4];
            float a3 = WtB[291 + i * 4];
            acc0.x += a0 * bb.x; acc0.y += a0 * bb.y; acc0.z += a0 * bb.z; acc0.w += a0 * bb.w;
            acc1.x += a1 * bb.x; acc1.y += a1 * bb.y; acc1.z += a1 * bb.z; acc1.w += a1 * bb.w;
            acc2.x += a2 * bb.x; acc2.y += a2 * bb.y; acc2.z += a2 * bb.z; acc2.w += a2 * bb.w;
            acc3.x += a3 * bb.x; acc3.y += a3 * bb.y; acc3.z += a3 * bb.z; acc3.w += a3 * bb.w;
        }
    }
    __syncthreads();
    // zbuf[ks][row(16)][nq][4] over Os region; row = rgq*4+jr
    if (t < 208) {
        int base = ((ks * 16 + rgq * 4) * 13 + nq) * 4;
        *reinterpret_cast<float4*>(smem + 1552 + base)       = acc0;
        *reinterpret_cast<float4*>(smem + 1552 + base + 52)  = acc1;
        *reinterpret_cast<float4*>(smem + 1552 + base + 104) = acc2;
        *reinterpret_cast<float4*>(smem + 1552 + base + 156) = acc3;
    }
    __syncthreads();
    if (t < 208) {
        int r = t / 13, nq2 = t - r * 13;
        int o0 = (r * 13 + nq2) * 4;
        float4 s0 = *reinterpret_cast<const float4*>(smem + 1552 + o0);
        float4 s1 = *reinterpret_cast<const float4*>(smem + 1552 + o0 + 832);
        float4 s2 = *reinterpret_cast<const float4*>(smem + 1552 + o0 + 1664);
        float4 s3 = *reinterpret_cast<const float4*>(smem + 1552 + o0 + 2496);
        float4 s;
        s.x = s0.x + s1.x + s2.x + s3.x;
        s.y = s0.y + s1.y + s2.y + s3.y;
        s.z = s0.z + s1.z + s2.z + s3.z;
        s.w = s0.w + s1.w + s2.w + s3.w;
        *reinterpret_cast<float4*>(zp + (size_t)kc * ZPSTR +
            ((size_t)(Bi * 384 + ot * 16 + r)) * 52 + nq2 * 4) = s;
    }
}

// ---------------------------------------------------------------------------
// Kernel 5: sum 4 split-K partials + bias, bilinear 7x7 -> 56x56
// one block per (B, ch) plane: 6144 blocks; nontemporal float4 stores
// ---------------------------------------------------------------------------
__global__ __launch_bounds__(256) void k_up(const float* __restrict__ zp,
                                            const float* __restrict__ b2,
                                            float* __restrict__ out) {
    int blk = blockIdx.x;          // 16*384
    int Bi = blk / 384, ch = blk - Bi * 384;
    __shared__ float zL[52];
    __shared__ float tmp[56][8];   // +1 pad col
    int t = threadIdx.x;
    if (t < 49) {
        size_t base = (size_t)(Bi * 384 + ch) * 52 + t;
        zL[t] = zp[base] + zp[base + ZPSTR] + zp[base + 2 * (size_t)ZPSTR]
              + zp[base + 3 * (size_t)ZPSTR] + b2[ch];
    }
    __syncthreads();
    for (int idx = t; idx < 392; idx += 256) {
        int h = idx / 7, iw = idx % 7;
        float sh = (h - 3.5f) * 0.125f;
        int ih0; float fh;
        if (sh <= 0.f)      { ih0 = 0; fh = 0.f; }
        else if (sh >= 6.f) { ih0 = 6; fh = 0.f; }
        else                { ih0 = (int)sh; fh = sh - (float)ih0; }
        int ih1 = min(ih0 + 1, 6);
        float z0 = zL[ih0 * 7 + iw];
        tmp[h][iw] = z0 + fh * (zL[ih1 * 7 + iw] - z0);
    }
    __syncthreads();
    size_t obase = ((size_t)Bi * 384 + ch) * (size_t)NPIX;
    for (int q = t; q < 784; q += 256) {          // 784 float4 quads
        int h = q / 14, qw = q % 14;
        vf4 o4;
#pragma unroll
        for (int j = 0; j < 4; ++j) {
            int w = qw * 4 + j;
            float sw = (w - 3.5f) * 0.125f;
            int iw0; float fw;
            if (sw <= 0.f)      { iw0 = 0; fw = 0.f; }
            else if (sw >= 6.f) { iw0 = 6; fw = 0.f; }
            else                { iw0 = (int)sw; fw = sw - (float)iw0; }
            int iw1 = min(iw0 + 1, 6);
            float t0 = tmp[h][iw0];
            o4[j] = t0 + fw * (tmp[h][iw1] - t0);
        }
        __builtin_nontemporal_store(o4,
            reinterpret_cast<vf4*>(out + obase + (size_t)q * 4));
    }
}

// ---------------------------------------------------------------------------
extern "C" void kernel_launch(void* const* d_in, const int* in_sizes, int n_in,
                              void* d_out, int out_size, void* d_ws, size_t ws_size,
                              hipStream_t stream) {
    const float* x      = (const float*)d_in[0];
    const float* proj_w = (const float*)d_in[1];
    const float* proj_b = (const float*)d_in[2];
    const float* alpha  = (const float*)d_in[3];
    const float* beta   = (const float*)d_in[4];
    const float* w2     = (const float*)d_in[5];
    const float* b2     = (const float*)d_in[6];
    float* out = (float*)d_out;
    float* ws  = (float*)d_ws;

    float* x_cat  = ws;                          // 344064 floats
    float* y_cat  = ws + (size_t)344064;         // 1720320 floats
    float* osmall = y_cat + (size_t)OCH * P_PAD; // 301056 floats
    float* zp     = osmall + (size_t)301056;     // 4*319488 = 1277952 floats
    // total ws usage: ~14.6 MB

    k_pool  <<<dim3(6144),   256, 0, stream>>>(x, x_cat);
    k_gemm1 <<<dim3(14, 30), 256, 0, stream>>>(proj_w, proj_b, x_cat, y_cat);
    k_attn  <<<dim3(128),    512, 0, stream>>>(y_cat, alpha, beta, osmall);
    k_gemm2s<<<dim3(1536),   256, 0, stream>>>(osmall, w2, zp);
    k_up    <<<dim3(6144),   256, 0, stream>>>(zp, b2, out);
}